// Round 1
// baseline (1106.820 us; speedup 1.0000x reference)
//
#include <hip/hip_runtime.h>
#include <stdint.h>

#define Bn   2
#define Sn   2048
#define Dn   1024
#define Hn   16
#define HDn  64
#define M1n  4096      // Bn*Sn
#define NQKV 3072
#define SCALEF 0.125f  // 64^-0.5

typedef __bf16 bf16_t;
typedef bf16_t bf16x8 __attribute__((ext_vector_type(8)));
typedef float  floatx4 __attribute__((ext_vector_type(4)));

__device__ __forceinline__ unsigned short f2b(float f) {
  union { float f; unsigned u; } v; v.f = f;
  unsigned r = v.u + 0x7fffu + ((v.u >> 16) & 1u);   // RNE
  return (unsigned short)(r >> 16);
}

__device__ __forceinline__ bf16x8 ldfrag(const unsigned short* p) {
  return *(const bf16x8*)p;
}

// ---------------- fp32 -> bf16 cast ----------------
__global__ __launch_bounds__(256) void cvt_f32_bf16(const float* __restrict__ in,
                                                    unsigned short* __restrict__ out, int n) {
  int i = (blockIdx.x * 256 + threadIdx.x) * 4;
  if (i < n) {
    float4 v = *(const float4*)(in + i);
    unsigned short o[4] = { f2b(v.x), f2b(v.y), f2b(v.z), f2b(v.w) };
    *(uint2*)(out + i) = *(const uint2*)o;
  }
}

// ---------------- generic bf16 GEMM + bias: C[M,N] = A[M,K]*B[K,N] + bias ----------------
// A row-major bf16, B row-major bf16 (transposed into LDS), out bf16 or f32.
template<bool F32OUT>
__global__ __launch_bounds__(256) void gemm_bias(
    const unsigned short* __restrict__ A,
    const unsigned short* __restrict__ Bw,
    const float* __restrict__ bias,
    void* __restrict__ Cv,
    int M, int N, int K)
{
  __shared__ unsigned short As[64][40];   // [m][k], pad 40 (80B pitch, 16B-aligned)
  __shared__ unsigned short Bs[64][40];   // [n][k] transposed
  const int t = threadIdx.x;
  const int n0 = blockIdx.x * 64;
  const int m0 = blockIdx.y * 64;
  const int wave = t >> 6, lane = t & 63, quad = lane >> 4, l16 = lane & 15;
  const int wm = (wave >> 1) * 32, wn = (wave & 1) * 32;
  floatx4 acc[2][2] = {};
  const int arow = t >> 2, acg = t & 3;   // A staging: 64 rows x (4 x 8 elems)
  const int brow = t >> 3, bcg = t & 7;   // B staging: 32 k-rows x (8 x 8 elems)
  const unsigned short* Ap = A + (size_t)(m0 + arow) * K + acg * 8;
  const unsigned short* Bp = Bw + (size_t)brow * N + n0 + bcg * 8;

  for (int k0 = 0; k0 < K; k0 += 32) {
    *(int4*)&As[arow][acg * 8] = *(const int4*)(Ap + k0);
    union { int4 v; unsigned short u[8]; } tb;
    tb.v = *(const int4*)(Bp + (size_t)k0 * N);
#pragma unroll
    for (int j = 0; j < 8; ++j) Bs[bcg * 8 + j][brow] = tb.u[j];
    __syncthreads();

    bf16x8 af[2], bf[2];
    af[0] = ldfrag(&As[wm + l16][quad * 8]);
    af[1] = ldfrag(&As[wm + 16 + l16][quad * 8]);
    bf[0] = ldfrag(&Bs[wn + l16][quad * 8]);
    bf[1] = ldfrag(&Bs[wn + 16 + l16][quad * 8]);
#pragma unroll
    for (int sm = 0; sm < 2; ++sm)
#pragma unroll
      for (int sn = 0; sn < 2; ++sn)
        acc[sm][sn] = __builtin_amdgcn_mfma_f32_16x16x32_bf16(af[sm], bf[sn], acc[sm][sn], 0, 0, 0);
    __syncthreads();
  }

#pragma unroll
  for (int sm = 0; sm < 2; ++sm)
#pragma unroll
    for (int sn = 0; sn < 2; ++sn) {
      const int n = n0 + wn + sn * 16 + l16;
      const float bv = bias[n];
#pragma unroll
      for (int r = 0; r < 4; ++r) {
        const int m = m0 + wm + sm * 16 + quad * 4 + r;
        const float val = acc[sm][sn][r] + bv;
        if (F32OUT) ((float*)Cv)[(size_t)m * N + n] = val;
        else        ((unsigned short*)Cv)[(size_t)m * N + n] = f2b(val);
      }
    }
}

// ---------------- scores = Q K^T * scale (per b,h) ----------------
__global__ __launch_bounds__(256) void attn_scores(
    const unsigned short* __restrict__ qkv,   // [4096, 3072] bf16
    float* __restrict__ attn)                 // [32, 2048, 2048]
{
  __shared__ unsigned short Qs[64][72];
  __shared__ unsigned short Ks[64][72];
  const int t = threadIdx.x;
  const int n0 = blockIdx.x * 64;
  const int m0 = blockIdx.y * 64;
  const int bh = blockIdx.z;
  const int b = bh >> 4, h = bh & 15;
  const size_t qbase = (size_t)b * Sn * NQKV + (size_t)h * HDn;
  const size_t kbase = qbase + Dn;
  const int row = t >> 2, seg = t & 3;
  {
    const unsigned short* gq = qkv + qbase + (size_t)(m0 + row) * NQKV + seg * 16;
    *(int4*)&Qs[row][seg * 16]     = *(const int4*)gq;
    *(int4*)&Qs[row][seg * 16 + 8] = *(const int4*)(gq + 8);
    const unsigned short* gk = qkv + kbase + (size_t)(n0 + row) * NQKV + seg * 16;
    *(int4*)&Ks[row][seg * 16]     = *(const int4*)gk;
    *(int4*)&Ks[row][seg * 16 + 8] = *(const int4*)(gk + 8);
  }
  __syncthreads();
  const int wave = t >> 6, lane = t & 63, quad = lane >> 4, l16 = lane & 15;
  const int wm = (wave >> 1) * 32, wn = (wave & 1) * 32;
  floatx4 acc[2][2] = {};
#pragma unroll
  for (int ks = 0; ks < 64; ks += 32) {
    bf16x8 af[2], bf[2];
    af[0] = ldfrag(&Qs[wm + l16][ks + quad * 8]);
    af[1] = ldfrag(&Qs[wm + 16 + l16][ks + quad * 8]);
    bf[0] = ldfrag(&Ks[wn + l16][ks + quad * 8]);
    bf[1] = ldfrag(&Ks[wn + 16 + l16][ks + quad * 8]);
#pragma unroll
    for (int sm = 0; sm < 2; ++sm)
#pragma unroll
      for (int sn = 0; sn < 2; ++sn)
        acc[sm][sn] = __builtin_amdgcn_mfma_f32_16x16x32_bf16(af[sm], bf[sn], acc[sm][sn], 0, 0, 0);
  }
  float* out = attn + (size_t)bh * Sn * Sn;
#pragma unroll
  for (int sm = 0; sm < 2; ++sm)
#pragma unroll
    for (int sn = 0; sn < 2; ++sn) {
      const int n = n0 + wn + sn * 16 + l16;
#pragma unroll
      for (int r = 0; r < 4; ++r) {
        const int m = m0 + wm + sm * 16 + quad * 4 + r;
        out[(size_t)m * Sn + n] = acc[sm][sn][r] * SCALEF;
      }
    }
}

// ---------------- row softmax in-place over attn rows of length 2048 ----------------
__global__ __launch_bounds__(256) void softmax_rows(float* __restrict__ attn) {
  const int row = blockIdx.x * 4 + (threadIdx.x >> 6);
  const int lane = threadIdx.x & 63;
  float4* p = (float4*)(attn + (size_t)row * Sn);
  float4 v[8];
  float mx = -1e30f;
#pragma unroll
  for (int i = 0; i < 8; ++i) {
    v[i] = p[i * 64 + lane];
    mx = fmaxf(mx, fmaxf(fmaxf(v[i].x, v[i].y), fmaxf(v[i].z, v[i].w)));
  }
#pragma unroll
  for (int off = 32; off > 0; off >>= 1) mx = fmaxf(mx, __shfl_xor(mx, off));
  float sum = 0.f;
#pragma unroll
  for (int i = 0; i < 8; ++i) {
    v[i].x = __expf(v[i].x - mx);
    v[i].y = __expf(v[i].y - mx);
    v[i].z = __expf(v[i].z - mx);
    v[i].w = __expf(v[i].w - mx);
    sum += v[i].x + v[i].y + v[i].z + v[i].w;
  }
#pragma unroll
  for (int off = 32; off > 0; off >>= 1) sum += __shfl_xor(sum, off);
  const float inv = 1.0f / sum;
#pragma unroll
  for (int i = 0; i < 8; ++i) {
    v[i].x *= inv; v[i].y *= inv; v[i].z *= inv; v[i].w *= inv;
    p[i * 64 + lane] = v[i];
  }
}

// ---------------- ctx = attn @ V (per b,h), ctx written as [4096, 1024] bf16 ----------------
__global__ __launch_bounds__(256) void attn_pv(
    const float* __restrict__ attn,           // [32,2048,2048]
    const unsigned short* __restrict__ qkv,   // [4096,3072] bf16
    unsigned short* __restrict__ ctx)         // [4096,1024] bf16
{
  __shared__ unsigned short As[64][72];   // [m][k] bf16(attn)
  __shared__ unsigned short Vs[64][72];   // [n][k] transposed V
  const int t = threadIdx.x;
  const int m0 = blockIdx.x * 64;
  const int bh = blockIdx.y;
  const int b = bh >> 4, h = bh & 15;
  const float* abase = attn + (size_t)bh * Sn * Sn;
  const size_t vbase = (size_t)b * Sn * NQKV + 2 * Dn + (size_t)h * HDn;
  const int row = t >> 2, seg = t & 3;
  const int wave = t >> 6, lane = t & 63, quad = lane >> 4, l16 = lane & 15;
  const int wm = (wave >> 1) * 32, wn = (wave & 1) * 32;
  floatx4 acc[2][2] = {};

  for (int k0 = 0; k0 < Sn; k0 += 64) {
    {
      const float* g = abase + (size_t)(m0 + row) * Sn + k0 + seg * 16;
      union { int4 v[2]; unsigned short u[16]; } tmp;
#pragma unroll
      for (int q4 = 0; q4 < 4; ++q4) {
        float4 fv = *(const float4*)(g + q4 * 4);
        tmp.u[q4 * 4 + 0] = f2b(fv.x);
        tmp.u[q4 * 4 + 1] = f2b(fv.y);
        tmp.u[q4 * 4 + 2] = f2b(fv.z);
        tmp.u[q4 * 4 + 3] = f2b(fv.w);
      }
      *(int4*)&As[row][seg * 16]     = tmp.v[0];
      *(int4*)&As[row][seg * 16 + 8] = tmp.v[1];
    }
    {
      const unsigned short* g = qkv + vbase + (size_t)(k0 + row) * NQKV + seg * 16;
      union { int4 v[2]; unsigned short u[16]; } tmp;
      tmp.v[0] = *(const int4*)g;
      tmp.v[1] = *(const int4*)(g + 8);
#pragma unroll
      for (int j = 0; j < 16; ++j) Vs[seg * 16 + j][row] = tmp.u[j];
    }
    __syncthreads();
#pragma unroll
    for (int ks = 0; ks < 64; ks += 32) {
      bf16x8 af[2], bf[2];
      af[0] = ldfrag(&As[wm + l16][ks + quad * 8]);
      af[1] = ldfrag(&As[wm + 16 + l16][ks + quad * 8]);
      bf[0] = ldfrag(&Vs[wn + l16][ks + quad * 8]);
      bf[1] = ldfrag(&Vs[wn + 16 + l16][ks + quad * 8]);
#pragma unroll
      for (int sm = 0; sm < 2; ++sm)
#pragma unroll
        for (int sn = 0; sn < 2; ++sn)
          acc[sm][sn] = __builtin_amdgcn_mfma_f32_16x16x32_bf16(af[sm], bf[sn], acc[sm][sn], 0, 0, 0);
    }
    __syncthreads();
  }

#pragma unroll
  for (int sm = 0; sm < 2; ++sm)
#pragma unroll
    for (int sn = 0; sn < 2; ++sn) {
      const int n = wn + sn * 16 + l16;
#pragma unroll
      for (int r = 0; r < 4; ++r) {
        const int m = m0 + wm + sm * 16 + quad * 4 + r;
        ctx[(size_t)(b * Sn + m) * Dn + h * HDn + n] = f2b(acc[sm][sn][r]);
      }
    }
}

extern "C" void kernel_launch(void* const* d_in, const int* in_sizes, int n_in,
                              void* d_out, int out_size, void* d_ws, size_t ws_size,
                              hipStream_t stream) {
  const float* x      = (const float*)d_in[0];
  const float* w_qkv  = (const float*)d_in[1];
  const float* b_qkv  = (const float*)d_in[2];
  const float* w_out  = (const float*)d_in[3];
  const float* b_out  = (const float*)d_in[4];

  float* outp = (float*)d_out;                     // [4096,1024]
  float* attn = outp + (size_t)M1n * Dn;           // [32,2048,2048]

  char* ws = (char*)d_ws;
  unsigned short* x_b    = (unsigned short*)ws;  ws += (size_t)M1n * Dn * 2;
  unsigned short* wqkv_b = (unsigned short*)ws;  ws += (size_t)Dn * NQKV * 2;
  unsigned short* wout_b = (unsigned short*)ws;  ws += (size_t)Dn * Dn * 2;
  unsigned short* qkv_b  = (unsigned short*)ws;  ws += (size_t)M1n * NQKV * 2;
  unsigned short* ctx_b  = (unsigned short*)ws;  ws += (size_t)M1n * Dn * 2;

  cvt_f32_bf16<<<(M1n * Dn) / 1024, 256, 0, stream>>>(x, x_b, M1n * Dn);
  cvt_f32_bf16<<<(Dn * NQKV) / 1024, 256, 0, stream>>>(w_qkv, wqkv_b, Dn * NQKV);
  cvt_f32_bf16<<<(Dn * Dn) / 1024, 256, 0, stream>>>(w_out, wout_b, Dn * Dn);

  gemm_bias<false><<<dim3(NQKV / 64, M1n / 64), 256, 0, stream>>>(
      x_b, wqkv_b, b_qkv, (void*)qkv_b, M1n, NQKV, Dn);

  attn_scores<<<dim3(Sn / 64, Sn / 64, Bn * Hn), 256, 0, stream>>>(qkv_b, attn);

  softmax_rows<<<(Bn * Hn * Sn) / 4, 256, 0, stream>>>(attn);

  attn_pv<<<dim3(Sn / 64, Bn * Hn), 256, 0, stream>>>(attn, qkv_b, ctx_b);

  gemm_bias<true><<<dim3(Dn / 64, M1n / 64), 256, 0, stream>>>(
      ctx_b, wout_b, b_out, (void*)outp, M1n, Dn, Dn);
}